// Round 3
// baseline (350.262 us; speedup 1.0000x reference)
//
#include <hip/hip_runtime.h>
#include <math.h>
#include <utility>

// Residual 4-level E8-root VQ — bit-exact vs numpy reference (R1 absmax 0.0).
// R3: fix R2's type-2 prefix-table index bit order. E[16] is built MSB-first
//   (index = 8*s(h1)+4*s(h2)+2*s(h3)+s(h4), matching R1's verified D-table
//   convention); R2 wrongly indexed it LSB-first (E[u & 15]). Index is a
//   template constant -> fix is compile-time only.
// Perf structure from R2 kept:
//  - Type-2 candidates via fold-expression over template ints (compile-time
//    folding of mask/parity logic).
//  - Depth-4 prefix sharing (E[16] over h0..h4): 3 adds + 1 fma + 2 selects
//    per type-2 candidate. Sharing is bit-exact: each table entry IS the
//    sequential-chain prefix fl-value; IEEE negation symmetry (fl(-a-b) =
//    -fl(a+b)) covers masks with bit0=1 via d2 = fmaf(+2,V,s).
//  - Inverted compare (keep = best <= d2): identical to strict-< first-index
//    tie-break scan in reference index order.
//  - qerr reduction fused via last-block ticket; partials summed in the EXACT
//    order of R1's separate reduce kernel.

constexpr int popc7(int v) {
  return ((v >> 0) & 1) + ((v >> 1) & 1) + ((v >> 2) & 1) + ((v >> 3) & 1) +
         ((v >> 4) & 1) + ((v >> 5) & 1) + ((v >> 6) & 1);
}

template <int T>
__device__ __forceinline__ void t2step(const float (&E)[16], float h5, float h6,
                                       float h7, float s, float& best,
                                       int& bi) {
#pragma clang fp contract(off)
  constexpr int p = popc7(T) & 1;       // bit0 of mask m = parity of t
  constexpr int u = T ^ (p ? 127 : 0);  // V-space sign bits (0=+) for h1..h7
  // E table is MSB-first: index = 8*s(h1) + 4*s(h2) + 2*s(h3) + s(h4)
  constexpr int s1 = u & 1, s2 = (u >> 1) & 1, s3 = (u >> 2) & 1,
                s4 = (u >> 3) & 1;
  constexpr int eidx = (s1 << 3) | (s2 << 2) | (s3 << 1) | s4;
  float v = E[eidx];                    // sequential prefix over h0..h4
  v = ((u >> 4) & 1) ? (v - h5) : (v + h5);
  v = ((u >> 5) & 1) ? (v - h6) : (v + h6);
  v = ((u >> 6) & 1) ? (v - h7) : (v + h7);
  // true dot = (p ? -V : V) exactly (IEEE negation symmetry step-by-step)
  const float d2 = p ? fmaf(2.f, v, s) : fmaf(-2.f, v, s);
  const bool keep = best <= d2;         // !(d2 < best): strict-< update
  best = keep ? best : d2;
  bi = keep ? bi : (112 + T);
}

template <int... Ts>
__device__ __forceinline__ void t2all(std::integer_sequence<int, Ts...>,
                                      const float (&E)[16], float h5, float h6,
                                      float h7, float s, float& best, int& bi) {
  (t2step<Ts>(E, h5, h6, h7, s, best, bi), ...);
}

__global__ __launch_bounds__(256) void e8_quant_kernel(
    const float* __restrict__ x, const float* __restrict__ roots,
    float* __restrict__ out, float* __restrict__ partials,
    int* __restrict__ counter, int nrow) {
#pragma clang fp contract(off)
  __shared__ float lroots[240 * 8];
  __shared__ float wred[4];
  __shared__ int sTicket;
  for (int t = threadIdx.x; t < 240 * 8; t += 256) lroots[t] = roots[t];
  __syncthreads();

  const int row = blockIdx.x * 256 + threadIdx.x;
  const bool active = row < nrow;
  float e = 0.f;

  if (active) {
    const float4 xa = *(const float4*)(x + (size_t)row * 8);
    const float4 xb = *(const float4*)(x + (size_t)row * 8 + 4);
    float xr[8] = {xa.x, xa.y, xa.z, xa.w, xb.x, xb.y, xb.z, xb.w};
    float qs[8] = {0.f, 0.f, 0.f, 0.f, 0.f, 0.f, 0.f, 0.f};
    float r[8];
#pragma unroll
    for (int k = 0; k < 8; ++k) r[k] = xr[k];

    float* out_idx = out + (size_t)nrow * 8;

#pragma unroll 1
    for (int lvl = 0; lvl < 4; ++lvl) {
      // res2, numpy pairwise order; s = fl(res2 + 2) (all |root|^2 == 2)
      const float q0 = r[0] * r[0], q1 = r[1] * r[1], q2 = r[2] * r[2],
                  q3 = r[3] * r[3], q4 = r[4] * r[4], q5 = r[5] * r[5],
                  q6 = r[6] * r[6], q7 = r[7] * r[7];
      const float res2 = ((q0 + q1) + (q2 + q3)) + ((q4 + q5) + (q6 + q7));
      const float s = res2 + 2.0f;

      float best = 3.4028235e38f;
      int bi = 0;

      // ---- Type-1: 112 roots, pairs (i<j), sign order (++,+-,-+,--) ----
      int ci = 0;
#pragma unroll
      for (int i = 0; i < 8; ++i) {
#pragma unroll
        for (int j = i + 1; j < 8; ++j) {
          const float a = r[i] + r[j];  // dot(+,+); -(a) = dot(-,-) exactly
          const float b = r[i] - r[j];  // dot(+,-); -(b) = dot(-,+) exactly
          {
            const float d2 = fmaf(-2.f, a, s);
            const bool keep = best <= d2;
            best = keep ? best : d2; bi = keep ? bi : ci;
          }
          {
            const float d2 = fmaf(-2.f, b, s);
            const bool keep = best <= d2;
            best = keep ? best : d2; bi = keep ? bi : ci + 1;
          }
          {
            const float d2 = fmaf(2.f, b, s);
            const bool keep = best <= d2;
            best = keep ? best : d2; bi = keep ? bi : ci + 2;
          }
          {
            const float d2 = fmaf(2.f, a, s);
            const bool keep = best <= d2;
            best = keep ? best : d2; bi = keep ? bi : ci + 3;
          }
          ci += 4;
        }
      }

      // ---- Type-2: 128 roots; sequential-prefix tree to depth 4 ----
      const float h0 = 0.5f * r[0], h1 = 0.5f * r[1], h2 = 0.5f * r[2],
                  h3 = 0.5f * r[3], h4 = 0.5f * r[4], h5 = 0.5f * r[5],
                  h6 = 0.5f * r[6], h7 = 0.5f * r[7];
      const float A0 = h0 + h1, A1 = h0 - h1;
      const float B0 = A0 + h2, B1 = A0 - h2, B2 = A1 + h2, B3 = A1 - h2;
      const float C0 = B0 + h3, C1 = B0 - h3, C2 = B1 + h3, C3 = B1 - h3,
                  C4 = B2 + h3, C5 = B2 - h3, C6 = B3 + h3, C7 = B3 - h3;
      // MSB-first: E[8*s1+4*s2+2*s3+s4]
      const float E[16] = {C0 + h4, C0 - h4, C1 + h4, C1 - h4,
                           C2 + h4, C2 - h4, C3 + h4, C3 - h4,
                           C4 + h4, C4 - h4, C5 + h4, C5 - h4,
                           C6 + h4, C6 - h4, C7 + h4, C7 - h4};
      t2all(std::make_integer_sequence<int, 128>{}, E, h5, h6, h7, s, best, bi);

      out_idx[(size_t)lvl * nrow + row] = (float)bi;

      // gather winning root from LDS; update qsum and residual (ref order)
      const float4 ra = *(const float4*)(lroots + bi * 8);
      const float4 rb = *(const float4*)(lroots + bi * 8 + 4);
      qs[0] += ra.x; qs[1] += ra.y; qs[2] += ra.z; qs[3] += ra.w;
      qs[4] += rb.x; qs[5] += rb.y; qs[6] += rb.z; qs[7] += rb.w;
#pragma unroll
      for (int k = 0; k < 8; ++k) r[k] = xr[k] - qs[k];
    }

    // quantized_ste = (qsum + x) - x
    float o[8];
#pragma unroll
    for (int k = 0; k < 8; ++k) o[k] = (qs[k] + xr[k]) - xr[k];
    *(float4*)(out + (size_t)row * 8) = make_float4(o[0], o[1], o[2], o[3]);
    *(float4*)(out + (size_t)row * 8 + 4) = make_float4(o[4], o[5], o[6], o[7]);

#pragma unroll
    for (int k = 0; k < 8; ++k) e = fmaf(r[k], r[k], e);
  }

  // block reduction of e -> partials[blockIdx.x]
#pragma unroll
  for (int off = 32; off > 0; off >>= 1) e += __shfl_down(e, off, 64);
  const int lane = threadIdx.x & 63, wv = threadIdx.x >> 6;
  if (lane == 0) wred[wv] = e;
  __syncthreads();
  if (threadIdx.x == 0)
    partials[blockIdx.x] = (wred[0] + wred[1]) + (wred[2] + wred[3]);

  // ---- fused final reduction: last block to finish does it ----
  __threadfence();  // release: partials[blockIdx.x] visible device-scope
  if (threadIdx.x == 0) sTicket = atomicAdd(counter, 1);
  __syncthreads();
  if (sTicket == (int)gridDim.x - 1) {
    __threadfence();  // acquire: other blocks' partials
    __syncthreads();  // wred reuse safety
    float e2 = 0.f;
    const int n = (int)gridDim.x;
    for (int i = threadIdx.x; i < n; i += 256) e2 += partials[i];
#pragma unroll
    for (int off = 32; off > 0; off >>= 1) e2 += __shfl_down(e2, off, 64);
    if (lane == 0) wred[wv] = e2;
    __syncthreads();
    if (threadIdx.x == 0) {
      const float scale = 1.0f / (float)((size_t)nrow * 8);  // 1/2^22 exact
      out[(size_t)nrow * 12] =
          ((wred[0] + wred[1]) + (wred[2] + wred[3])) * scale;
    }
  }
}

extern "C" void kernel_launch(void* const* d_in, const int* in_sizes, int n_in,
                              void* d_out, int out_size, void* d_ws,
                              size_t ws_size, hipStream_t stream) {
  const float* x = (const float*)d_in[0];
  const float* roots = (const float*)d_in[1];
  float* out = (float*)d_out;
  int* counter = (int*)d_ws;
  float* partials = (float*)((char*)d_ws + 1024);

  const int nrow = in_sizes[0] / 8;
  const int nblocks = (nrow + 255) / 256;

  hipMemsetAsync(counter, 0, sizeof(int), stream);
  e8_quant_kernel<<<nblocks, 256, 0, stream>>>(x, roots, out, partials, counter,
                                               nrow);
}

// Round 4
// 140.160 us; speedup vs baseline: 2.4990x; 2.4990x over previous
//
#include <hip/hip_runtime.h>
#include <math.h>
#include <utility>

// Residual 4-level E8-root VQ — bit-exact argmin/quantized vs numpy reference
// (R1/R3 absmax 0.0). R4 changes:
//  - REMOVED ticket + __threadfence fusion (R3: every block's agent-release
//    fence emits buffer_wbl2 -> serialized L2 writeback storm, +275us stall;
//    VALU busy-time was identical R1 vs R3 at ~68.6us, all regression stall).
//    qerr now: one relaxed device-scope float atomicAdd per block into
//    out[qerr_pos] (zeroed via hipMemsetAsync pre-launch). Nondeterministic
//    summation order -> ~1e-6 relative deviation, far inside threshold.
//  - Chunked argmin: 4 independent scans with LOCAL indices 0..63 (inline
//    constants -> v_cndmask never needs a 32-bit literal, in VOP2 *or* VOP3
//    form -> no per-candidate v_mov). Chunks cover candidate ranges
//    [0,64) [64,112) [112,176) [176,240); merged in chunk order with
//    keep-on-<= -> identical winner + first-index tie-break as single scan.
// Numerics (all verified R1/R3, unchanged):
//  - d2 = fmaf(-+2, dot, s), s = fl(res2+2) (|root|^2 == 2 exactly).
//  - type-1 dots exact (single add, other 6 products exact zeros).
//  - type-2 dots: sequential-k chain via MSB-first prefix table E[16] over
//    h0..h4 + IEEE negation symmetry for odd-parity masks.
//  - res2 in numpy pairwise order; fp contract off.

constexpr int popc7(int v) {
  return ((v >> 0) & 1) + ((v >> 1) & 1) + ((v >> 2) & 1) + ((v >> 3) & 1) +
         ((v >> 4) & 1) + ((v >> 5) & 1) + ((v >> 6) & 1);
}

template <int T>
__device__ __forceinline__ void t2step(const float (&E)[16], float h5, float h6,
                                       float h7, float s, float& bestC,
                                       int& biC, float& bestD, int& biD) {
#pragma clang fp contract(off)
  constexpr int p = popc7(T) & 1;       // bit0 of mask m = parity of t
  constexpr int u = T ^ (p ? 127 : 0);  // V-space sign bits (0=+) for h1..h7
  // E table is MSB-first: index = 8*s(h1) + 4*s(h2) + 2*s(h3) + s(h4)
  constexpr int s1 = u & 1, s2 = (u >> 1) & 1, s3 = (u >> 2) & 1,
                s4 = (u >> 3) & 1;
  constexpr int eidx = (s1 << 3) | (s2 << 2) | (s3 << 1) | s4;
  float v = E[eidx];                    // sequential prefix over h0..h4
  v = ((u >> 4) & 1) ? (v - h5) : (v + h5);
  v = ((u >> 5) & 1) ? (v - h6) : (v + h6);
  v = ((u >> 6) & 1) ? (v - h7) : (v + h7);
  // true dot = (p ? -V : V) exactly (IEEE negation symmetry step-by-step)
  const float d2 = p ? fmaf(2.f, v, s) : fmaf(-2.f, v, s);
  constexpr int loc = T & 63;           // inline-const local index
  if constexpr ((T >> 6) == 0) {
    const bool k = bestC <= d2;         // strict-< first-index update
    bestC = k ? bestC : d2;
    biC = k ? biC : loc;
  } else {
    const bool k = bestD <= d2;
    bestD = k ? bestD : d2;
    biD = k ? biD : loc;
  }
}

template <int... Ts>
__device__ __forceinline__ void t2all(std::integer_sequence<int, Ts...>,
                                      const float (&E)[16], float h5, float h6,
                                      float h7, float s, float& bestC, int& biC,
                                      float& bestD, int& biD) {
  (t2step<Ts>(E, h5, h6, h7, s, bestC, biC, bestD, biD), ...);
}

__global__ __launch_bounds__(256) void e8_quant_kernel(
    const float* __restrict__ x, const float* __restrict__ roots,
    float* __restrict__ out, int nrow) {
#pragma clang fp contract(off)
  __shared__ float lroots[240 * 8];
  __shared__ float wred[4];
  for (int t = threadIdx.x; t < 240 * 8; t += 256) lroots[t] = roots[t];
  __syncthreads();

  const int row = blockIdx.x * 256 + threadIdx.x;
  const bool active = row < nrow;
  float e = 0.f;

  if (active) {
    const float4 xa = *(const float4*)(x + (size_t)row * 8);
    const float4 xb = *(const float4*)(x + (size_t)row * 8 + 4);
    float xr[8] = {xa.x, xa.y, xa.z, xa.w, xb.x, xb.y, xb.z, xb.w};
    float qs[8] = {0.f, 0.f, 0.f, 0.f, 0.f, 0.f, 0.f, 0.f};
    float r[8];
#pragma unroll
    for (int k = 0; k < 8; ++k) r[k] = xr[k];

    float* out_idx = out + (size_t)nrow * 8;

#pragma unroll 1
    for (int lvl = 0; lvl < 4; ++lvl) {
      // res2, numpy pairwise order; s = fl(res2 + 2)
      const float q0 = r[0] * r[0], q1 = r[1] * r[1], q2 = r[2] * r[2],
                  q3 = r[3] * r[3], q4 = r[4] * r[4], q5 = r[5] * r[5],
                  q6 = r[6] * r[6], q7 = r[7] * r[7];
      const float res2 = ((q0 + q1) + (q2 + q3)) + ((q4 + q5) + (q6 + q7));
      const float s = res2 + 2.0f;

      // four chunk scans, local indices 0..63 (inline consts)
      const float FMAX = 3.4028235e38f;
      float bestA = FMAX, bestB = FMAX, bestC = FMAX, bestD = FMAX;
      int biA = 0, biB = 0, biC = 0, biD = 0;

      // ---- Type-1: 112 roots, pairs (i<j), sign order (++,+-,-+,--) ----
      {
        int ci = 0;
#pragma unroll
        for (int i = 0; i < 8; ++i) {
#pragma unroll
          for (int j = i + 1; j < 8; ++j) {
            const float a = r[i] + r[j];  // dot(+,+); -(a)=dot(-,-) exact
            const float b = r[i] - r[j];  // dot(+,-); -(b)=dot(-,+) exact
            const float d0 = fmaf(-2.f, a, s);
            const float d1 = fmaf(-2.f, b, s);
            const float d2v = fmaf(2.f, b, s);
            const float d3 = fmaf(2.f, a, s);
            if (ci < 64) {  // folds at unroll time; groups of 4 never straddle
              { const bool k = bestA <= d0; bestA = k ? bestA : d0; biA = k ? biA : ci + 0; }
              { const bool k = bestA <= d1; bestA = k ? bestA : d1; biA = k ? biA : ci + 1; }
              { const bool k = bestA <= d2v; bestA = k ? bestA : d2v; biA = k ? biA : ci + 2; }
              { const bool k = bestA <= d3; bestA = k ? bestA : d3; biA = k ? biA : ci + 3; }
            } else {
              { const bool k = bestB <= d0; bestB = k ? bestB : d0; biB = k ? biB : ci - 64; }
              { const bool k = bestB <= d1; bestB = k ? bestB : d1; biB = k ? biB : ci - 63; }
              { const bool k = bestB <= d2v; bestB = k ? bestB : d2v; biB = k ? biB : ci - 62; }
              { const bool k = bestB <= d3; bestB = k ? bestB : d3; biB = k ? biB : ci - 61; }
            }
            ci += 4;
          }
        }
      }

      // ---- Type-2: 128 roots; MSB-first prefix tree to depth 4 ----
      const float h0 = 0.5f * r[0], h1 = 0.5f * r[1], h2 = 0.5f * r[2],
                  h3 = 0.5f * r[3], h4 = 0.5f * r[4], h5 = 0.5f * r[5],
                  h6 = 0.5f * r[6], h7 = 0.5f * r[7];
      const float A0 = h0 + h1, A1 = h0 - h1;
      const float B0 = A0 + h2, B1 = A0 - h2, B2 = A1 + h2, B3 = A1 - h2;
      const float C0 = B0 + h3, C1 = B0 - h3, C2 = B1 + h3, C3 = B1 - h3,
                  C4 = B2 + h3, C5 = B2 - h3, C6 = B3 + h3, C7 = B3 - h3;
      const float E[16] = {C0 + h4, C0 - h4, C1 + h4, C1 - h4,
                           C2 + h4, C2 - h4, C3 + h4, C3 - h4,
                           C4 + h4, C4 - h4, C5 + h4, C5 - h4,
                           C6 + h4, C6 - h4, C7 + h4, C7 - h4};
      t2all(std::make_integer_sequence<int, 128>{}, E, h5, h6, h7, s, bestC,
            biC, bestD, biD);

      // ---- merge chunks in index order (keep-on-<= = first-index) ----
      float best = bestA;
      int bi = biA;
      { const bool k = best <= bestB; best = k ? best : bestB; bi = k ? bi : biB + 64; }
      { const bool k = best <= bestC; best = k ? best : bestC; bi = k ? bi : biC + 112; }
      { const bool k = best <= bestD; best = k ? best : bestD; bi = k ? bi : biD + 176; }

      out_idx[(size_t)lvl * nrow + row] = (float)bi;

      // gather winning root from LDS; update qsum and residual (ref order)
      const float4 ra = *(const float4*)(lroots + bi * 8);
      const float4 rb = *(const float4*)(lroots + bi * 8 + 4);
      qs[0] += ra.x; qs[1] += ra.y; qs[2] += ra.z; qs[3] += ra.w;
      qs[4] += rb.x; qs[5] += rb.y; qs[6] += rb.z; qs[7] += rb.w;
#pragma unroll
      for (int k = 0; k < 8; ++k) r[k] = xr[k] - qs[k];
    }

    // quantized_ste = (qsum + x) - x
    float o[8];
#pragma unroll
    for (int k = 0; k < 8; ++k) o[k] = (qs[k] + xr[k]) - xr[k];
    *(float4*)(out + (size_t)row * 8) = make_float4(o[0], o[1], o[2], o[3]);
    *(float4*)(out + (size_t)row * 8 + 4) = make_float4(o[4], o[5], o[6], o[7]);

#pragma unroll
    for (int k = 0; k < 8; ++k) e = fmaf(r[k], r[k], e);
  }

  // block reduction of e, then ONE relaxed device-scope atomic per block.
  // No fences: nothing reads out[qerr_pos] until stream sync.
#pragma unroll
  for (int off = 32; off > 0; off >>= 1) e += __shfl_down(e, off, 64);
  const int lane = threadIdx.x & 63, wv = threadIdx.x >> 6;
  if (lane == 0) wred[wv] = e;
  __syncthreads();
  if (threadIdx.x == 0) {
    const float scale = 1.0f / (float)((size_t)nrow * 8);  // 1/2^22, exact
    const float part = ((wred[0] + wred[1]) + (wred[2] + wred[3])) * scale;
    atomicAdd(out + (size_t)nrow * 12, part);
  }
}

extern "C" void kernel_launch(void* const* d_in, const int* in_sizes, int n_in,
                              void* d_out, int out_size, void* d_ws,
                              size_t ws_size, hipStream_t stream) {
  const float* x = (const float*)d_in[0];
  const float* roots = (const float*)d_in[1];
  float* out = (float*)d_out;

  const int nrow = in_sizes[0] / 8;
  const int nblocks = (nrow + 255) / 256;

  // zero the qerr accumulator slot (d_out is poisoned 0xAA before each call)
  hipMemsetAsync(out + (size_t)nrow * 12, 0, sizeof(float), stream);
  e8_quant_kernel<<<nblocks, 256, 0, stream>>>(x, roots, out, nrow);
}

// Round 5
// 134.406 us; speedup vs baseline: 2.6060x; 1.0428x over previous
//
#include <hip/hip_runtime.h>
#include <math.h>
#include <utility>

// Residual 4-level E8-root VQ — bit-exact argmin vs numpy reference.
// R5: (1) v_min3_f32-based argmin scan in REVERSE index order (take-on-eq =
//     exact first-index tie-break; 5 ops per 2 candidates incl. best update);
//     (2) VOP3P packed fp32 (inline asm: v_pk_add_f32 / v_pk_fma_f32 with
//     op_sel broadcasts + neg_hi) — per-lane IEEE identical to scalar, so all
//     roundings match the verified R1/R3/R4 chain bit-for-bit;
//     (3) type-2 adjacent pairing: for even t, candidate t+1's effective sign
//     vector complements t's in bits 1..6 (parity flips), so both chains share
//     one (E[e], E[e^7]) register pair and 3 pk_adds (neg on opposite halves),
//     then one pk_fma with multiplier pair (-+2,+-2).
// Scan-order proof: chunks processed independently (D:176-239, C:112-175,
// B:64-111, A:0-63), each scanned in DESCENDING candidate order with
// new = min3(d2lo, d2hi, best); bi = (d2hi==new)?Lhi:bi; bi = (d2lo==new)?Llo:bi
// — on any tie the LAST eq-assign (lowest index) wins, and the incumbent
// always has a higher index. Chunk merge takes lower chunk on <=.
// qerr: per-block reduce + one relaxed device-scope atomicAdd (R4, verified).

typedef float f2 __attribute__((ext_vector_type(2)));

constexpr int popc7(int v) {
  return ((v >> 0) & 1) + ((v >> 1) & 1) + ((v >> 2) & 1) + ((v >> 3) & 1) +
         ((v >> 4) & 1) + ((v >> 5) & 1) + ((v >> 6) & 1);
}
constexpr int pr_i(int p) {
  int c = 0;
  for (int i = 0; i < 8; ++i)
    for (int j = i + 1; j < 8; ++j) {
      if (c == p) return i;
      ++c;
    }
  return 0;
}
constexpr int pr_j(int p) {
  int c = 0;
  for (int i = 0; i < 8; ++i)
    for (int j = i + 1; j < 8; ++j) {
      if (c == p) return j;
      ++c;
    }
  return 0;
}

// (a,b) = (src0[S0] + src1[S1], src0[S0] - src1[S1])  — broadcast + neg_hi
template <int S0, int S1>
__device__ __forceinline__ f2 mk_ab(f2 a, f2 b) {
  f2 d;
  if constexpr (S0 == 0 && S1 == 0)
    asm("v_pk_add_f32 %0, %1, %2 op_sel:[0,0] op_sel_hi:[0,0] neg_hi:[0,1]" : "=v"(d) : "v"(a), "v"(b));
  else if constexpr (S0 == 0 && S1 == 1)
    asm("v_pk_add_f32 %0, %1, %2 op_sel:[0,1] op_sel_hi:[0,1] neg_hi:[0,1]" : "=v"(d) : "v"(a), "v"(b));
  else if constexpr (S0 == 1 && S1 == 0)
    asm("v_pk_add_f32 %0, %1, %2 op_sel:[1,0] op_sel_hi:[1,0] neg_hi:[0,1]" : "=v"(d) : "v"(a), "v"(b));
  else
    asm("v_pk_add_f32 %0, %1, %2 op_sel:[1,1] op_sel_hi:[1,1] neg_hi:[0,1]" : "=v"(d) : "v"(a), "v"(b));
  return d;
}

__device__ __forceinline__ f2 pkmul(f2 a, f2 b) {
  f2 d;
  asm("v_pk_mul_f32 %0, %1, %2" : "=v"(d) : "v"(a), "v"(b));
  return d;
}

// d2 pairs: ca = (-2, 2). Variants pick multiplier pair via op_sel on src0.
__device__ __forceinline__ f2 pkfma_mm(f2 ca, f2 v, f2 ss) {  // (-2,-2)
  f2 d;
  asm("v_pk_fma_f32 %0, %1, %2, %3 op_sel:[0,0,0] op_sel_hi:[0,1,1]" : "=v"(d) : "v"(ca), "v"(v), "v"(ss));
  return d;
}
__device__ __forceinline__ f2 pkfma_pp(f2 ca, f2 v, f2 ss) {  // (2,2)
  f2 d;
  asm("v_pk_fma_f32 %0, %1, %2, %3 op_sel:[1,0,0] op_sel_hi:[1,1,1]" : "=v"(d) : "v"(ca), "v"(v), "v"(ss));
  return d;
}
template <int P>  // P=0: (-2,2) as-is; P=1: (2,-2) swapped
__device__ __forceinline__ f2 pkfma_sw(f2 ca, f2 v, f2 ss) {
  f2 d;
  if constexpr (P == 0)
    asm("v_pk_fma_f32 %0, %1, %2, %3" : "=v"(d) : "v"(ca), "v"(v), "v"(ss));
  else
    asm("v_pk_fma_f32 %0, %1, %2, %3 op_sel:[1,0,0] op_sel_hi:[0,1,1]" : "=v"(d) : "v"(ca), "v"(v), "v"(ss));
  return d;
}

// tail step 1: src0 = EP (optionally swapped), src1 = h5 bcast (H2 hi).
// lo lane: EP[sel] + (NEG? -h5 : h5); hi lane always opposite sign.
template <bool SW, bool NEG>
__device__ __forceinline__ f2 tail1(f2 ep, f2 h2p) {
  f2 d;
  if constexpr (!SW && !NEG)
    asm("v_pk_add_f32 %0, %1, %2 op_sel:[0,1] op_sel_hi:[1,1] neg_hi:[0,1]" : "=v"(d) : "v"(ep), "v"(h2p));
  else if constexpr (!SW && NEG)
    asm("v_pk_add_f32 %0, %1, %2 op_sel:[0,1] op_sel_hi:[1,1] neg_lo:[0,1]" : "=v"(d) : "v"(ep), "v"(h2p));
  else if constexpr (SW && !NEG)
    asm("v_pk_add_f32 %0, %1, %2 op_sel:[1,1] op_sel_hi:[0,1] neg_hi:[0,1]" : "=v"(d) : "v"(ep), "v"(h2p));
  else
    asm("v_pk_add_f32 %0, %1, %2 op_sel:[1,1] op_sel_hi:[0,1] neg_lo:[0,1]" : "=v"(d) : "v"(ep), "v"(h2p));
  return d;
}
// tail steps 2/3: src0 = v (normal), src1 = H3 bcast lo (h6) or hi (h7).
template <int SEL, bool NEG>
__device__ __forceinline__ f2 tailn(f2 v, f2 h3p) {
  f2 d;
  if constexpr (SEL == 0 && !NEG)
    asm("v_pk_add_f32 %0, %1, %2 op_sel:[0,0] op_sel_hi:[1,0] neg_hi:[0,1]" : "=v"(d) : "v"(v), "v"(h3p));
  else if constexpr (SEL == 0 && NEG)
    asm("v_pk_add_f32 %0, %1, %2 op_sel:[0,0] op_sel_hi:[1,0] neg_lo:[0,1]" : "=v"(d) : "v"(v), "v"(h3p));
  else if constexpr (SEL == 1 && !NEG)
    asm("v_pk_add_f32 %0, %1, %2 op_sel:[0,1] op_sel_hi:[1,1] neg_hi:[0,1]" : "=v"(d) : "v"(v), "v"(h3p));
  else
    asm("v_pk_add_f32 %0, %1, %2 op_sel:[0,1] op_sel_hi:[1,1] neg_lo:[0,1]" : "=v"(d) : "v"(v), "v"(h3p));
  return d;
}

// one type-2 adjacent pair (candidates 112+T, 112+T+1), T even, reverse scan
template <int T>
__device__ __forceinline__ void t2pair(const f2 (&EP)[8], f2 h2p, f2 h3p,
                                       f2 ca, f2 ss, float& best, int& bi) {
  constexpr int p = popc7(T) & 1;
  constexpr int u = T ^ (p ? 127 : 0);  // lo-cand sign bits (0=+) for h1..h7
  constexpr int e = (((u >> 0) & 1) << 3) | (((u >> 1) & 1) << 2) |
                    (((u >> 2) & 1) << 1) | ((u >> 3) & 1);  // MSB-first
  constexpr bool sw = ((e >> 2) & 1) != 0;   // canon has bit2 == 0
  constexpr int canon = sw ? (e ^ 7) : e;
  constexpr int slot = (canon & 3) | ((canon >> 3) << 2);
  constexpr bool n5 = ((u >> 4) & 1) != 0;
  constexpr bool n6 = ((u >> 5) & 1) != 0;
  constexpr bool n7 = ((u >> 6) & 1) != 0;
  f2 v = tail1<sw, n5>(EP[slot], h2p);
  v = tailn<0, n6>(v, h3p);
  v = tailn<1, n7>(v, h3p);
  // dot_lo = (p? -v.x : v.x), dot_hi has flipped parity -> mult pair
  f2 d2 = pkfma_sw<p>(ca, v, ss);  // (fl(s-2*dot_lo), fl(s-2*dot_hi))
  const float nb = __builtin_fminf(__builtin_fminf(d2.x, d2.y), best);
  bi = (d2.y == nb) ? ((T & 63) + 1) : bi;  // higher index first
  bi = (d2.x == nb) ? (T & 63) : bi;        // lower index wins ties
  best = nb;
}

template <int BASE, int... K>
__device__ __forceinline__ void t2scan(std::integer_sequence<int, K...>,
                                       const f2 (&EP)[8], f2 h2p, f2 h3p,
                                       f2 ca, f2 ss, float& best, int& bi) {
  (t2pair<BASE - 2 * K>(EP, h2p, h3p, ca, ss, best, bi), ...);
}

// one type-1 (i,j) 4-group, reverse scan (ci+3, ci+2, ci+1, ci)
template <int PID>
__device__ __forceinline__ void t1pair(const f2 (&R)[4], f2 ca, f2 ss,
                                       float& best, int& bi) {
  constexpr int i = pr_i(PID), j = pr_j(PID);
  f2 ab = mk_ab<i & 1, j & 1>(R[i / 2], R[j / 2]);  // (ri+rj, ri-rj)
  f2 P = pkfma_mm(ca, ab, ss);  // (fl(s-2a)=d2_ci, fl(s-2b)=d2_ci+1)
  f2 Q = pkfma_pp(ca, ab, ss);  // (fl(s+2a)=d2_ci+3, fl(s+2b)=d2_ci+2)
  constexpr int l = 4 * PID - (PID >= 16 ? 64 : 0);  // chunk-local base
  const float nb = __builtin_fminf(__builtin_fminf(Q.x, Q.y), best);
  bi = (Q.x == nb) ? (l + 3) : bi;
  bi = (Q.y == nb) ? (l + 2) : bi;
  const float nb2 = __builtin_fminf(__builtin_fminf(P.x, P.y), nb);
  bi = (P.y == nb2) ? (l + 1) : bi;
  bi = (P.x == nb2) ? (l + 0) : bi;
  best = nb2;
}

template <int... K>
__device__ __forceinline__ void t1scanB(std::integer_sequence<int, K...>,
                                        const f2 (&R)[4], f2 ca, f2 ss,
                                        float& best, int& bi) {
  (t1pair<27 - K>(R, ca, ss, best, bi), ...);  // PID 27..16
}
template <int... K>
__device__ __forceinline__ void t1scanA(std::integer_sequence<int, K...>,
                                        const f2 (&R)[4], f2 ca, f2 ss,
                                        float& best, int& bi) {
  (t1pair<15 - K>(R, ca, ss, best, bi), ...);  // PID 15..0
}

__global__ __launch_bounds__(256) void e8_quant_kernel(
    const float* __restrict__ x, const float* __restrict__ roots,
    float* __restrict__ out, int nrow) {
#pragma clang fp contract(off)
  __shared__ float lroots[240 * 8];
  __shared__ float wred[4];
  for (int t = threadIdx.x; t < 240 * 8; t += 256) lroots[t] = roots[t];
  __syncthreads();

  const int row = blockIdx.x * 256 + threadIdx.x;
  const bool active = row < nrow;
  float e = 0.f;

  if (active) {
    const float4 xa = *(const float4*)(x + (size_t)row * 8);
    const float4 xb = *(const float4*)(x + (size_t)row * 8 + 4);
    f2 X[4] = {{xa.x, xa.y}, {xa.z, xa.w}, {xb.x, xb.y}, {xb.z, xb.w}};
    f2 Qs[4] = {{0.f, 0.f}, {0.f, 0.f}, {0.f, 0.f}, {0.f, 0.f}};
    f2 R[4];
#pragma unroll
    for (int k = 0; k < 4; ++k) R[k] = X[k];

    f2 CA = {-2.f, 2.f};
    f2 HF = {0.5f, 0.5f};
    float* out_idx = out + (size_t)nrow * 8;

#pragma unroll 1
    for (int lvl = 0; lvl < 4; ++lvl) {
      // res2, numpy pairwise order; s = fl(res2 + 2)
      const float q0 = R[0].x * R[0].x, q1 = R[0].y * R[0].y,
                  q2 = R[1].x * R[1].x, q3 = R[1].y * R[1].y,
                  q4 = R[2].x * R[2].x, q5 = R[2].y * R[2].y,
                  q6 = R[3].x * R[3].x, q7 = R[3].y * R[3].y;
      const float res2 = ((q0 + q1) + (q2 + q3)) + ((q4 + q5) + (q6 + q7));
      const float s = res2 + 2.0f;
      f2 SS = {s, s};

      // halves and MSB-first prefix tree over h0..h4 (packed +- pairs)
      f2 H0 = pkmul(R[0], HF), H1 = pkmul(R[1], HF), H2 = pkmul(R[2], HF),
         H3 = pkmul(R[3], HF);
      f2 A = mk_ab<0, 1>(H0, H0);     // (h0+h1, h0-h1)
      f2 B01 = mk_ab<0, 0>(A, H1);    // (A0+h2, A0-h2)
      f2 B23 = mk_ab<1, 0>(A, H1);    // (A1+h2, A1-h2)
      f2 C01 = mk_ab<0, 1>(B01, H1);  // (B0+h3, B0-h3)
      f2 C23 = mk_ab<1, 1>(B01, H1);
      f2 C45 = mk_ab<0, 1>(B23, H1);
      f2 C67 = mk_ab<1, 1>(B23, H1);
      const float h4 = H2.x;
      // EP[slot] = (E[canon], E[canon^7]); E[e]=C[e>>1] + (e&1 ? -h4 : h4)
      f2 EP[8];
      EP[0].x = C01.x + h4; EP[0].y = C23.y - h4;  // (E0,  E7)
      EP[1].x = C01.x - h4; EP[1].y = C23.y + h4;  // (E1,  E6)
      EP[2].x = C01.y + h4; EP[2].y = C23.x - h4;  // (E2,  E5)
      EP[3].x = C01.y - h4; EP[3].y = C23.x + h4;  // (E3,  E4)
      EP[4].x = C45.x + h4; EP[4].y = C67.y - h4;  // (E8,  E15)
      EP[5].x = C45.x - h4; EP[5].y = C67.y + h4;  // (E9,  E14)
      EP[6].x = C45.y + h4; EP[6].y = C67.x - h4;  // (E10, E13)
      EP[7].x = C45.y - h4; EP[7].y = C67.x + h4;  // (E11, E12)

      const float FMAX = 3.4028235e38f;
      float bestA = FMAX, bestB = FMAX, bestC = FMAX, bestD = FMAX;
      int biA = 0, biB = 0, biC = 0, biD = 0;

      // reverse-order chunk scans
      t2scan<126>(std::make_integer_sequence<int, 32>{}, EP, H2, H3, CA, SS,
                  bestD, biD);  // t = 126..64  (cands 176..239)
      t2scan<62>(std::make_integer_sequence<int, 32>{}, EP, H2, H3, CA, SS,
                 bestC, biC);   // t = 62..0    (cands 112..175)
      t1scanB(std::make_integer_sequence<int, 12>{}, R, CA, SS, bestB, biB);
      t1scanA(std::make_integer_sequence<int, 16>{}, R, CA, SS, bestA, biA);

      // merge, lower chunk wins ties (<=)
      float best = bestD;
      int bi = biD + 176;
      { const bool k = bestC <= best; const int g = biC + 112;
        best = k ? bestC : best; bi = k ? g : bi; }
      { const bool k = bestB <= best; const int g = biB + 64;
        best = k ? bestB : best; bi = k ? g : bi; }
      { const bool k = bestA <= best;
        best = k ? bestA : best; bi = k ? biA : bi; }

      out_idx[(size_t)lvl * nrow + row] = (float)bi;

      // gather winning root from LDS; update qsum and residual (ref order)
      const float4 ra = *(const float4*)(lroots + bi * 8);
      const float4 rb = *(const float4*)(lroots + bi * 8 + 4);
      Qs[0].x += ra.x; Qs[0].y += ra.y; Qs[1].x += ra.z; Qs[1].y += ra.w;
      Qs[2].x += rb.x; Qs[2].y += rb.y; Qs[3].x += rb.z; Qs[3].y += rb.w;
#pragma unroll
      for (int k = 0; k < 4; ++k) {
        R[k].x = X[k].x - Qs[k].x;
        R[k].y = X[k].y - Qs[k].y;
      }
    }

    // quantized_ste = (qsum + x) - x
    float o[8];
#pragma unroll
    for (int k = 0; k < 4; ++k) {
      o[2 * k] = (Qs[k].x + X[k].x) - X[k].x;
      o[2 * k + 1] = (Qs[k].y + X[k].y) - X[k].y;
    }
    *(float4*)(out + (size_t)row * 8) = make_float4(o[0], o[1], o[2], o[3]);
    *(float4*)(out + (size_t)row * 8 + 4) = make_float4(o[4], o[5], o[6], o[7]);

#pragma unroll
    for (int k = 0; k < 4; ++k) {
      e = fmaf(R[k].x, R[k].x, e);
      e = fmaf(R[k].y, R[k].y, e);
    }
  }

  // block reduction of e, then ONE relaxed device-scope atomic per block
#pragma unroll
  for (int off = 32; off > 0; off >>= 1) e += __shfl_down(e, off, 64);
  const int lane = threadIdx.x & 63, wv = threadIdx.x >> 6;
  if (lane == 0) wred[wv] = e;
  __syncthreads();
  if (threadIdx.x == 0) {
    const float scale = 1.0f / (float)((size_t)nrow * 8);  // 1/2^22, exact
    const float part = ((wred[0] + wred[1]) + (wred[2] + wred[3])) * scale;
    atomicAdd(out + (size_t)nrow * 12, part);
  }
}

extern "C" void kernel_launch(void* const* d_in, const int* in_sizes, int n_in,
                              void* d_out, int out_size, void* d_ws,
                              size_t ws_size, hipStream_t stream) {
  const float* x = (const float*)d_in[0];
  const float* roots = (const float*)d_in[1];
  float* out = (float*)d_out;

  const int nrow = in_sizes[0] / 8;
  const int nblocks = (nrow + 255) / 256;

  hipMemsetAsync(out + (size_t)nrow * 12, 0, sizeof(float), stream);
  e8_quant_kernel<<<nblocks, 256, 0, stream>>>(x, roots, out, nrow);
}